// Round 10
// baseline (213.072 us; speedup 1.0000x reference)
//
#include <hip/hip_runtime.h>

#define T_DIM 2048
#define D_DIM 1024
#define H_DIM 1024
#define B_DIM 4

typedef __attribute__((ext_vector_type(8))) __bf16 bf16x8;
typedef __attribute__((ext_vector_type(4))) float f32x4;
typedef __attribute__((ext_vector_type(8))) unsigned short us8;

__device__ __forceinline__ unsigned short f2b(float f) {
  union { float f; unsigned int u; } x; x.f = f;
  unsigned int r = x.u + 0x7fffu + ((x.u >> 16) & 1u);
  return (unsigned short)(r >> 16);
}
__device__ __forceinline__ float b2f(unsigned short b) {
  union { unsigned int u; float f; } x; x.u = ((unsigned int)b) << 16;
  return x.f;
}

__device__ __forceinline__ void async16(unsigned short* l, const unsigned short* g) {
  __builtin_amdgcn_global_load_lds((const __attribute__((address_space(1))) void*)g,
                                   (__attribute__((address_space(3))) void*)l,
                                   16, 0, 0);
}

// ---------------- fused weights prep: 4x f32->bf16 cvt + bias concat ----------------
__global__ __launch_bounds__(256) void prep_kernel(const float* __restrict__ ew,
                                                   const float* __restrict__ kw,
                                                   const float* __restrict__ qw,
                                                   const float* __restrict__ vw,
                                                   const float* __restrict__ kb,
                                                   const float* __restrict__ qb,
                                                   const float* __restrict__ vb,
                                                   unsigned short* __restrict__ oe,
                                                   unsigned short* __restrict__ okqv,
                                                   float* __restrict__ ob) {
  int bid = blockIdx.x;
  if (bid == 4096) {               // bias concat: 3072 floats
    #pragma unroll
    for (int k = 0; k < 3; k++) {
      int f4 = threadIdx.x + k * 256;
      int fi = f4 * 4;
      const float* src = fi < 1024 ? kb + fi : (fi < 2048 ? qb + (fi - 1024) : vb + (fi - 2048));
      *(float4*)(&ob[fi]) = *(const float4*)src;
    }
    return;
  }
  int i = bid * 256 + threadIdx.x;
  int seg = i >> 18;
  int off = i & 262143;
  const float* in = seg == 0 ? ew : (seg == 1 ? kw : (seg == 2 ? qw : vw));
  unsigned short* out = seg == 0 ? oe : okqv + (size_t)(seg - 1) * 1048576;
  float4 v = ((const float4*)in)[off];
  ushort4 o;
  o.x = f2b(v.x); o.y = f2b(v.y); o.z = f2b(v.z); o.w = f2b(v.w);
  ((ushort4*)out)[off] = o;
}

// ---------------- tiled transpose (bf16 -> bf16, for VT) ----------------
__global__ __launch_bounds__(256) void transpose_kernel(const unsigned short* __restrict__ in,
                                                        unsigned short* __restrict__ out,
                                                        int inLD, size_t sIn, int R, size_t sOut) {
  __shared__ unsigned short tile[32][33];
  int c0 = blockIdx.x * 32, r0 = blockIdx.y * 32;
  int tx = threadIdx.x & 31, ty = threadIdx.x >> 5;
  const unsigned short* I = in + (size_t)blockIdx.z * sIn;
  #pragma unroll
  for (int i = 0; i < 32; i += 8)
    tile[ty + i][tx] = I[(size_t)(r0 + ty + i) * inLD + (c0 + tx)];
  __syncthreads();
  unsigned short* O = out + (size_t)blockIdx.z * sOut;
  #pragma unroll
  for (int i = 0; i < 32; i += 8)
    O[(size_t)(c0 + ty + i) * R + (r0 + tx)] = tile[tx][ty + i];
}

#define BAR_ asm volatile("s_barrier" ::: "memory")
#define LGK0_ asm volatile("s_waitcnt lgkmcnt(0)" ::: "memory")
#define VM8_ asm volatile("s_waitcnt vmcnt(8)" ::: "memory")
#define VM6_ asm volatile("s_waitcnt vmcnt(6)" ::: "memory")
#define VM4_ asm volatile("s_waitcnt vmcnt(4)" ::: "memory")
#define VM0_ asm volatile("s_waitcnt vmcnt(0)" ::: "memory")

#define FRG(base, row, ks) \
  (*(const bf16x8*)((base) + (row) * 64 + ((((ks) << 2) | hi) ^ (lo & 7)) * 8))

// ============ 128x256 B^T GEMM, triple-buffered, 1 barrier / K-tile (R9, unchanged) ============
#define STGA3(t, bb, u) async16(smem + (bb) * 24576 + (u) * 4096 + tid * 8, \
                                A + (size_t)((u) * 64 + rl0) * lda + (t) * 64 + ce)
#define STGB3(t, bb, u) async16(smem + (bb) * 24576 + 8192 + (u) * 4096 + tid * 8, \
                                Bm + (size_t)((u) * 64 + rl0) * ldb + (t) * 64 + ce)
#define STGTILE(t, bb) do { STGA3(t, bb, 0); STGA3(t, bb, 1); \
    STGB3(t, bb, 0); STGB3(t, bb, 1); STGB3(t, bb, 2); STGB3(t, bb, 3); } while (0)

#define LOADFRAGS(bA, bB)                                            \
  _Pragma("unroll") for (int m_ = 0; m_ < 4; m_++) {                 \
    af[m_][0] = FRG(bA, wr * 64 + m_ * 16 + lo, 0);                  \
    af[m_][1] = FRG(bA, wr * 64 + m_ * 16 + lo, 1);                  \
  }                                                                  \
  _Pragma("unroll") for (int n_ = 0; n_ < 4; n_++) {                 \
    bg[n_][0] = FRG(bB, wc * 64 + n_ * 16 + lo, 0);                  \
    bg[n_][1] = FRG(bB, wc * 64 + n_ * 16 + lo, 1);                  \
  }

#define MFMA32_                                                          \
  __builtin_amdgcn_s_setprio(1);                                         \
  _Pragma("unroll") for (int ks_ = 0; ks_ < 2; ks_++)                    \
    _Pragma("unroll") for (int m_ = 0; m_ < 4; m_++)                     \
      _Pragma("unroll") for (int n_ = 0; n_ < 4; n_++)                   \
        acc[m_][n_] = __builtin_amdgcn_mfma_f32_16x16x32_bf16(           \
            af[m_][ks_], bg[n_][ks_], acc[m_][n_], 0, 0, 0);             \
  __builtin_amdgcn_s_setprio(0);

template <int OMODE, bool BIAS>
__global__ __launch_bounds__(512, 2)
void gemm8_kernel(const unsigned short* __restrict__ A,
                  const unsigned short* __restrict__ Bm,
                  const float* __restrict__ bias,
                  float* __restrict__ Cf, unsigned short* __restrict__ Cb,
                  int N, int K, int lda, int ldb,
                  size_t sAb, size_t sBb, size_t sCb) {
  __shared__ __align__(16) unsigned short smem[73728];   // 144 KiB

  int gx = gridDim.x;
  int nwg = gx * gridDim.y;
  int flat = blockIdx.x + gx * blockIdx.y;
  int cpx = nwg >> 3;
  int f2 = (flat & 7) * cpx + (flat >> 3);
  int bn = f2 % gx, bm = f2 / gx;
  int bz = blockIdx.z;

  A  += (size_t)bz * sAb + (size_t)bm * 128 * lda;
  Bm += (size_t)bz * sBb + (size_t)bn * 256 * ldb;

  int tid = threadIdx.x;
  int lane = tid & 63, wid = tid >> 6;
  int wr = wid >> 2, wc = wid & 3;
  int lo = lane & 15, hi = lane >> 4;
  int rl0 = tid >> 3;
  int ce = 8 * ((tid & 7) ^ (rl0 & 7));

  int nt = K / 64;

  bf16x8 af[4][2], bg[4][2];
  f32x4 acc[4][4] = {};

  STGTILE(0, 0);
  STGTILE(1, 1);
  VM6_; BAR_;

  int cur = 0;
  for (int t = 0; t < nt - 2; t++) {
    const unsigned short* bA = smem + cur * 24576;
    const unsigned short* bB = bA + 8192;
    LOADFRAGS(bA, bB)
    int b2 = cur + 2; if (b2 >= 3) b2 -= 3;
    STGTILE(t + 2, b2);
    MFMA32_
    VM6_; BAR_;
    cur = (cur + 1 == 3) ? 0 : cur + 1;
  }
  {
    const unsigned short* bA = smem + cur * 24576;
    const unsigned short* bB = bA + 8192;
    LOADFRAGS(bA, bB)
    MFMA32_
    VM0_; BAR_;
    cur = (cur + 1 == 3) ? 0 : cur + 1;
  }
  {
    const unsigned short* bA = smem + cur * 24576;
    const unsigned short* bB = bA + 8192;
    LOADFRAGS(bA, bB)
    MFMA32_
  }

  __syncthreads();
  int row0 = bm * 128, col0 = bn * 256;
  size_t coff = (size_t)bz * sCb;

  if (OMODE == 1) {
    unsigned short* ep = smem;   // [128][264]
    #pragma unroll
    for (int n = 0; n < 4; n++) {
      int cl = wc * 64 + n * 16 + lo;
      float bv = BIAS ? bias[col0 + cl] : 0.f;
      #pragma unroll
      for (int m = 0; m < 4; m++) {
        int rl = wr * 64 + m * 16 + hi * 4;
        #pragma unroll
        for (int j = 0; j < 4; j++)
          ep[(rl + j) * 264 + cl] = f2b(acc[m][n][j] + bv);
      }
    }
    __syncthreads();
    #pragma unroll
    for (int it = 0; it < 8; it++) {
      int idx = it * 512 + tid, r = idx >> 5, c = idx & 31;
      *(uint4*)(Cb + coff + (size_t)(row0 + r) * N + col0 + c * 8) =
          *(const uint4*)(ep + r * 264 + c * 8);
    }
  } else {   // f32 out
    float* ep = (float*)smem;    // [64][260]
    #pragma unroll
    for (int half = 0; half < 2; half++) {
      __syncthreads();
      if (wr == half) {
        #pragma unroll
        for (int n = 0; n < 4; n++) {
          int cl = wc * 64 + n * 16 + lo;
          #pragma unroll
          for (int m = 0; m < 4; m++) {
            int rl = m * 16 + hi * 4;
            #pragma unroll
            for (int j = 0; j < 4; j++) ep[(rl + j) * 260 + cl] = acc[m][n][j];
          }
        }
      }
      __syncthreads();
      #pragma unroll
      for (int it = 0; it < 8; it++) {
        int idx = it * 512 + tid, r = idx >> 6, c = idx & 63;
        *(float4*)(Cf + coff + (size_t)(row0 + half * 64 + r) * N + col0 + c * 4) =
            *(const float4*)(ep + r * 260 + c * 4);
      }
    }
  }
}

// ============ embt: m = x^T @ W^T + b with A-transpose fused in (f32 x -> bf16 LDS) ============
// Same 128x256 triple-buffer pipeline; A staged via reg round-trip (T14 split:
// f32 loads for tile t+3 issued in iter t, ds_writes in iter t+1 -> full K-tile of slack).
__global__ __launch_bounds__(512, 2)
void embt_kernel(const float* __restrict__ X,              // [B][H][T] f32
                 const unsigned short* __restrict__ Bm,    // emb_w bf16 [1024][1024]
                 const float* __restrict__ bias,
                 unsigned short* __restrict__ Cb) {        // m_bf [8192][1024]
  __shared__ __align__(16) unsigned short smem[73728];
  const int ldb = 1024;
  int gx = gridDim.x;                      // 4
  int nwg = gx * gridDim.y;                // 256
  int flat = blockIdx.x + gx * blockIdx.y;
  int cpx = nwg >> 3;
  int f2x = (flat & 7) * cpx + (flat >> 3);
  int bn = f2x % gx, bm = f2x / gx;
  int batch = bm >> 4;
  const float* Xb = X + (size_t)batch * H_DIM * T_DIM + (bm & 15) * 128;
  Bm += (size_t)bn * 256 * ldb;

  int tid = threadIdx.x;
  int lane = tid & 63, wid = tid >> 6;
  int wr = wid >> 2, wc = wid & 3;
  int lo = lane & 15, hi = lane >> 4;
  int rl0 = tid >> 3;
  int ce = 8 * ((tid & 7) ^ (rl0 & 7));
  int h_loc = tid >> 3, t_off = (tid & 7) * 16;

  float fv[16];
  // load f32 strip for K-tile t into fv (16 contiguous t for one h-row)
  #define ELOAD(t) do { \
    const float* xs_ = Xb + (size_t)((t) * 64 + h_loc) * T_DIM + t_off;               \
    float4 a_ = *(const float4*)xs_,      b_ = *(const float4*)(xs_ + 4);             \
    float4 c_ = *(const float4*)(xs_ + 8), d_ = *(const float4*)(xs_ + 12);           \
    fv[0]=a_.x; fv[1]=a_.y; fv[2]=a_.z; fv[3]=a_.w;                                   \
    fv[4]=b_.x; fv[5]=b_.y; fv[6]=b_.z; fv[7]=b_.w;                                   \
    fv[8]=c_.x; fv[9]=c_.y; fv[10]=c_.z; fv[11]=c_.w;                                 \
    fv[12]=d_.x; fv[13]=d_.y; fv[14]=d_.z; fv[15]=d_.w; } while (0)
  // transposed + swizzled write of fv into A-region of buf bb
  #define EWRITE(bb) do { \
    unsigned short* ab_ = smem + (bb) * 24576;                                        \
    _Pragma("unroll") for (int j_ = 0; j_ < 16; j_++) {                               \
      int tr_ = t_off + j_;                                                           \
      ab_[tr_ * 64 + (((h_loc >> 3) ^ (tr_ & 7)) << 3) + (h_loc & 7)] = f2b(fv[j_]);  \
    } } while (0)

  const int nt = 16;   // K = 1024
  bf16x8 af[4][2], bg[4][2];
  f32x4 acc[4][4] = {};

  // prologue: A(0),A(1) into LDS; A(2) in fv; B(0),B(1) async
  ELOAD(0); EWRITE(0);
  ELOAD(1); EWRITE(1);
  ELOAD(2);
  STGB3(0, 0, 0); STGB3(0, 0, 1); STGB3(0, 0, 2); STGB3(0, 0, 3);
  STGB3(1, 1, 0); STGB3(1, 1, 1); STGB3(1, 1, 2); STGB3(1, 1, 3);
  LGK0_; VM4_; BAR_;

  int cur = 0;
  for (int t = 0; t < nt - 2; t++) {
    const unsigned short* bA = smem + cur * 24576;
    const unsigned short* bB = bA + 8192;
    LOADFRAGS(bA, bB)
    int b2 = cur + 2; if (b2 >= 3) b2 -= 3;
    EWRITE(b2);                       // A(t+2), data loaded in iter t-1
    if (t + 3 < nt) ELOAD(t + 3);     // prefetch A(t+3) into regs
    STGB3(t + 2, b2, 0); STGB3(t + 2, b2, 1); STGB3(t + 2, b2, 2); STGB3(t + 2, b2, 3);
    MFMA32_
    VM4_; BAR_;                       // retire B(t+1) (A handled by lgkm chain)
    cur = (cur + 1 == 3) ? 0 : cur + 1;
  }
  {
    const unsigned short* bA = smem + cur * 24576;
    const unsigned short* bB = bA + 8192;
    LOADFRAGS(bA, bB)
    MFMA32_
    VM0_; BAR_;
    cur = (cur + 1 == 3) ? 0 : cur + 1;
  }
  {
    const unsigned short* bA = smem + cur * 24576;
    const unsigned short* bB = bA + 8192;
    LOADFRAGS(bA, bB)
    MFMA32_
  }

  __syncthreads();
  int row0 = bm * 128, col0 = bn * 256;
  unsigned short* ep = smem;   // [128][264]
  #pragma unroll
  for (int n = 0; n < 4; n++) {
    int cl = wc * 64 + n * 16 + lo;
    float bv = bias[col0 + cl];
    #pragma unroll
    for (int m = 0; m < 4; m++) {
      int rl = wr * 64 + m * 16 + hi * 4;
      #pragma unroll
      for (int j = 0; j < 4; j++)
        ep[(rl + j) * 264 + cl] = f2b(acc[m][n][j] + bv);
    }
  }
  __syncthreads();
  #pragma unroll
  for (int it = 0; it < 8; it++) {
    int idx = it * 512 + tid, r = idx >> 5, c = idx & 31;
    *(uint4*)(Cb + (size_t)(row0 + r) * D_DIM + col0 + c * 8) =
        *(const uint4*)(ep + r * 264 + c * 8);
  }
}

// ============ gemmL: 256x256 8-phase (R7-validated), bf16 out, causal skip bn<bm ============
#define STGAH(t, h) do { \
    unsigned short* d_ = ldsA + ((t) & 1) * 16384 + (h) * 8192 + tid * 8;            \
    const unsigned short* s_ = A + (size_t)((h) * 128 + rl0) * lda + (t) * 64 + ce;  \
    async16(d_, s_); async16(d_ + 4096, s_ + (size_t)64 * lda); } while (0)
#define STGBH(t, h) do { \
    unsigned short* d_ = ldsB + ((t) & 1) * 16384 + (h) * 8192 + tid * 8;            \
    const unsigned short* s_ = Bm + (size_t)((h) * 128 + rl0) * ldb + (t) * 64 + ce; \
    async16(d_, s_); async16(d_ + 4096, s_ + (size_t)64 * ldb); } while (0)

#define LDA_(bA, mb)                                                   \
  _Pragma("unroll") for (int m_ = 0; m_ < 4; m_++) {                   \
    int row_ = wr * 128 + ((mb) + m_) * 16 + lo;                       \
    af[m_][0] = FRG(bA, row_, 0);                                      \
    af[m_][1] = FRG(bA, row_, 1);                                      \
  }

#define LDB_(bB, nb, bgv)                                              \
  _Pragma("unroll") for (int n_ = 0; n_ < 2; n_++) {                   \
    int row_ = wc * 64 + ((nb) + n_) * 16 + lo;                        \
    bgv[n_][0] = FRG(bB, row_, 0);                                     \
    bgv[n_][1] = FRG(bB, row_, 1);                                     \
  }

#define MM_(mb, nb, bgv)                                                             \
  __builtin_amdgcn_s_setprio(1);                                                     \
  _Pragma("unroll") for (int m_ = 0; m_ < 4; m_++)                                   \
    _Pragma("unroll") for (int n_ = 0; n_ < 2; n_++) {                               \
      acc[(mb) + m_][(nb) + n_] = __builtin_amdgcn_mfma_f32_16x16x32_bf16(           \
          af[m_][0], bgv[n_][0], acc[(mb) + m_][(nb) + n_], 0, 0, 0);                \
      acc[(mb) + m_][(nb) + n_] = __builtin_amdgcn_mfma_f32_16x16x32_bf16(           \
          af[m_][1], bgv[n_][1], acc[(mb) + m_][(nb) + n_], 0, 0, 0);                \
    }                                                                                \
  __builtin_amdgcn_s_setprio(0);

__global__ __launch_bounds__(512, 2)
void gemmL_kernel(const unsigned short* __restrict__ A,
                  const unsigned short* __restrict__ Bm,
                  unsigned short* __restrict__ Cb,
                  int N, int K, int lda, int ldb,
                  size_t sAb, size_t sBb, size_t sCb) {
  __shared__ __align__(16) unsigned short smem[65536];   // 128 KiB
  unsigned short* ldsA = smem;
  unsigned short* ldsB = smem + 32768;

  int gx = gridDim.x;
  int nwg = gx * gridDim.y;
  int flat = blockIdx.x + gx * blockIdx.y;
  int cpx = nwg >> 3;
  int f2x = (flat & 7) * cpx + (flat >> 3);
  int bn = f2x % gx, bm = f2x / gx;
  int bz = blockIdx.z;
  if (bn < bm) return;       // causal skip (t-tile < s-tile)

  A  += (size_t)bz * sAb + (size_t)bm * 256 * lda;
  Bm += (size_t)bz * sBb + (size_t)bn * 256 * ldb;

  int tid = threadIdx.x;
  int lane = tid & 63, wid = tid >> 6;
  int wr = wid >> 2, wc = wid & 3;
  int lo = lane & 15, hi = lane >> 4;
  int rl0 = tid >> 3;
  int ce = 8 * ((tid & 7) ^ (rl0 & 7));

  int nt = K / 64;

  bf16x8 af[4][2], bg0[2][2], bg1[2][2];
  f32x4 acc[8][4] = {};

  STGAH(0, 0); STGAH(0, 1); STGBH(0, 0); STGBH(0, 1);
  STGAH(1, 0); STGAH(1, 1); STGBH(1, 0); STGBH(1, 1);
  VM8_; BAR_;

  const unsigned short* bA0 = ldsA;
  const unsigned short* bB0 = ldsB;
  const unsigned short* bA1 = ldsA + 16384;
  const unsigned short* bB1 = ldsB + 16384;

  int nIter = nt >> 1;
  for (int i = 0; i < nIter; i++) {
    bool last = (i == nIter - 1);
    int ta = 2 * i, tb = ta + 1;
    LDA_(bA0, 0) LDB_(bB0, 0, bg0)
    BAR_; MM_(0, 0, bg0) BAR_;
    LDB_(bB0, 2, bg1)
    BAR_; MM_(0, 2, bg1) BAR_;
    LDA_(bA0, 4)
    if (!last) STGBH(ta + 2, 0);
    BAR_; MM_(4, 0, bg0) BAR_;
    if (!last) { STGAH(ta + 2, 0); STGBH(ta + 2, 1); }
    BAR_; MM_(4, 2, bg1)
    if (last) { VM0_; } else { VM6_; }
    BAR_;
    LDA_(bA1, 0) LDB_(bB1, 0, bg0)
    if (!last) STGAH(ta + 2, 1);
    BAR_; MM_(0, 0, bg0) BAR_;
    LDB_(bB1, 2, bg1)
    BAR_; MM_(0, 2, bg1) BAR_;
    LDA_(bA1, 4)
    if (!last) STGBH(tb + 2, 0);
    BAR_; MM_(4, 0, bg0) BAR_;
    if (!last) { STGAH(tb + 2, 0); STGBH(tb + 2, 1); STGAH(tb + 2, 1); }
    BAR_; MM_(4, 2, bg1)
    if (!last) VM8_;
    BAR_;
  }

  __syncthreads();
  int row0 = bm * 256, col0 = bn * 256;
  size_t coff = (size_t)bz * sCb;
  unsigned short* ep = smem;   // [128][264], 2 halves
  #pragma unroll
  for (int half = 0; half < 2; half++) {
    __syncthreads();
    if (wr == half) {
      #pragma unroll
      for (int n = 0; n < 4; n++) {
        int cl = wc * 64 + n * 16 + lo;
        #pragma unroll
        for (int m = 0; m < 8; m++) {
          int rl = m * 16 + hi * 4;
          #pragma unroll
          for (int j = 0; j < 4; j++)
            ep[(rl + j) * 264 + cl] = f2b(acc[m][n][j]);
        }
      }
    }
    __syncthreads();
    #pragma unroll
    for (int it = 0; it < 8; it++) {
      int idx = it * 512 + tid, r = idx >> 5, c = idx & 31;
      *(uint4*)(Cb + coff + (size_t)(row0 + half * 128 + r) * N + col0 + c * 8) =
          *(const uint4*)(ep + r * 264 + c * 8);
    }
  }
}

// ============ Paired causal PV (R9, unchanged) ============
#define PSTGA(t, bb, u) async16(smem + (bb) * 16384 + (u) * 4096 + tid * 8, \
                                Ap + (size_t)((u) * 64 + rl0) * T_DIM + (t) * 64 + ce)
#define PSTGB(t, bb, u) async16(smem + (bb) * 16384 + 8192 + (u) * 4096 + tid * 8, \
                                Bp + (size_t)((u) * 64 + rl0) * T_DIM + (t) * 64 + ce)
#define PSTG(t, bb) do { PSTGA(t, bb, 0); PSTGA(t, bb, 1); \
                         PSTGB(t, bb, 0); PSTGB(t, bb, 1); } while (0)

#define PVFRAGS(bA, bB)                                              \
  _Pragma("unroll") for (int m_ = 0; m_ < 4; m_++) {                 \
    af[m_][0] = FRG(bA, wr * 64 + m_ * 16 + lo, 0);                  \
    af[m_][1] = FRG(bA, wr * 64 + m_ * 16 + lo, 1);                  \
  }                                                                  \
  _Pragma("unroll") for (int n_ = 0; n_ < 2; n_++) {                 \
    bg[n_][0] = FRG(bB, wc * 32 + n_ * 16 + lo, 0);                  \
    bg[n_][1] = FRG(bB, wc * 32 + n_ * 16 + lo, 1);                  \
  }

#define PVMFMA_                                                          \
  __builtin_amdgcn_s_setprio(1);                                         \
  _Pragma("unroll") for (int ks_ = 0; ks_ < 2; ks_++)                    \
    _Pragma("unroll") for (int m_ = 0; m_ < 4; m_++)                     \
      _Pragma("unroll") for (int n_ = 0; n_ < 2; n_++)                   \
        acc[m_][n_] = __builtin_amdgcn_mfma_f32_16x16x32_bf16(           \
            af[m_][ks_], bg[ks_ == 0 ? 0 : 0][0], acc[m_][n_], 0, 0, 0); \
  __builtin_amdgcn_s_setprio(0);

#undef PVMFMA_
#define PVMFMA_                                                          \
  __builtin_amdgcn_s_setprio(1);                                         \
  _Pragma("unroll") for (int ks_ = 0; ks_ < 2; ks_++)                    \
    _Pragma("unroll") for (int m_ = 0; m_ < 4; m_++)                     \
      _Pragma("unroll") for (int n_ = 0; n_ < 2; n_++)                   \
        acc[m_][n_] = __builtin_amdgcn_mfma_f32_16x16x32_bf16(           \
            af[m_][ks_], bg[n_][ks_], acc[m_][n_], 0, 0, 0);             \
  __builtin_amdgcn_s_setprio(0);

__global__ __launch_bounds__(512, 2)
void pv_kernel(const unsigned short* __restrict__ probs,
               const unsigned short* __restrict__ VT,
               const unsigned short* __restrict__ mres,
               float* __restrict__ out) {
  __shared__ __align__(16) unsigned short smem[49152];   // 96 KiB
  int bn = blockIdx.x;
  int jj = blockIdx.y;
  int bz = blockIdx.z;
  int tid = threadIdx.x;
  int lane = tid & 63, wid = tid >> 6;
  int wr = wid >> 2, wc = wid & 3;
  int lo = lane & 15, hi = lane >> 4;
  int rl0 = tid >> 3;
  int ce = 8 * ((tid & 7) ^ (rl0 & 7));

  const unsigned short* Bp = VT + (size_t)bz * D_DIM * T_DIM + (size_t)(bn * 128) * T_DIM;

  #pragma unroll 1
  for (int seg = 0; seg < 2; seg++) {
    int jt = (seg == 0) ? jj : (15 - jj);
    int nt = ((seg == 0) ? (jj + 1) : (16 - jj)) * 2;
    const unsigned short* Ap = probs + (size_t)bz * T_DIM * T_DIM + (size_t)(jt * 128) * T_DIM;

    bf16x8 af[4][2], bg[2][2];
    f32x4 acc[4][2] = {};

    PSTG(0, 0);
    PSTG(1, 1);
    VM4_; BAR_;

    int cur = 0;
    for (int t = 0; t < nt - 2; t++) {
      const unsigned short* bA = smem + cur * 16384;
      const unsigned short* bB = bA + 8192;
      PVFRAGS(bA, bB)
      int b2 = cur + 2; if (b2 >= 3) b2 -= 3;
      PSTG(t + 2, b2);
      PVMFMA_
      VM4_; BAR_;
      cur = (cur + 1 == 3) ? 0 : cur + 1;
    }
    {
      const unsigned short* bA = smem + cur * 16384;
      const unsigned short* bB = bA + 8192;
      PVFRAGS(bA, bB)
      PVMFMA_
      VM0_; BAR_;
      cur = (cur + 1 == 3) ? 0 : cur + 1;
    }
    {
      const unsigned short* bA = smem + cur * 16384;
      const unsigned short* bB = bA + 8192;
      PVFRAGS(bA, bB)
      PVMFMA_
    }

    __syncthreads();
    float* ep = (float*)smem;
    #pragma unroll
    for (int n = 0; n < 2; n++) {
      int dl = wc * 32 + n * 16 + lo;
      #pragma unroll
      for (int m = 0; m < 4; m++) {
        int tl = wr * 64 + m * 16 + hi * 4;
        #pragma unroll
        for (int j = 0; j < 4; j++) {
          float v = acc[m][n][j] +
              b2f(mres[((size_t)bz * T_DIM + jt * 128 + tl + j) * D_DIM + bn * 128 + dl]);
          ep[dl * 132 + tl + j] = v;
        }
      }
    }
    __syncthreads();
    #pragma unroll
    for (int it = 0; it < 8; it++) {
      int idx = it * 512 + tid, r = idx >> 5, c = idx & 31;
      *(float4*)(out + ((size_t)bz * D_DIM + bn * 128 + r) * T_DIM + jt * 128 + c * 4) =
          *(const float4*)(ep + r * 132 + c * 4);
    }
    __syncthreads();
  }
}

// ---------------- softmax stats (bf16 logitsT rows) ----------------
__device__ __forceinline__ float wred_max(float v) {
  #pragma unroll
  for (int o = 32; o > 0; o >>= 1) v = fmaxf(v, __shfl_down(v, o, 64));
  return v;
}
__device__ __forceinline__ float wred_sum(float v) {
  #pragma unroll
  for (int o = 32; o > 0; o >>= 1) v += __shfl_down(v, o, 64);
  return v;
}

__global__ __launch_bounds__(256) void softmax_stats_kernel(const unsigned short* __restrict__ lg,
                                                            float* __restrict__ smax,
                                                            float* __restrict__ sinv) {
  __shared__ float sb[4];
  int row = blockIdx.x;            // b*T + s
  int s = row & (T_DIM - 1);
  us8 v = ((const us8*)(lg + (size_t)row * T_DIM))[threadIdx.x];
  int tb = threadIdx.x * 8;
  float x[8];
  float mx = -3.4e38f;
  #pragma unroll
  for (int j = 0; j < 8; j++) {
    x[j] = (tb + j >= s) ? b2f(v[j]) : -3.4e38f;
    mx = fmaxf(mx, x[j]);
  }
  mx = wred_max(mx);
  if ((threadIdx.x & 63) == 0) sb[threadIdx.x >> 6] = mx;
  __syncthreads();
  mx = fmaxf(fmaxf(sb[0], sb[1]), fmaxf(sb[2], sb[3]));
  __syncthreads();
  float sum = 0.f;
  #pragma unroll
  for (int j = 0; j < 8; j++) sum += __expf(x[j] - mx);
  sum = wred_sum(sum);
  if ((threadIdx.x & 63) == 0) sb[threadIdx.x >> 6] = sum;
  __syncthreads();
  if (threadIdx.x == 0) {
    float tot = sb[0] + sb[1] + sb[2] + sb[3];
    smax[row] = mx;
    sinv[row] = 1.0f / (tot * 32.0f);
  }
}

// ---------------- normalize + transpose: probs[t][s] bf16 ----------------
__global__ __launch_bounds__(256) void probs_kernel(const unsigned short* __restrict__ lg,
                                                    const float* __restrict__ smax,
                                                    const float* __restrict__ sinv,
                                                    unsigned short* __restrict__ probs) {
  int bz = blockIdx.z;
  int t0 = blockIdx.x * 32, s0 = blockIdx.y * 32;
  if (s0 >= (((t0 >> 7) + 1) << 7)) return;
  __shared__ unsigned short tile[32][33];
  int tx = threadIdx.x & 31, ty = threadIdx.x >> 5;
  const unsigned short* L = lg + (size_t)bz * T_DIM * T_DIM;
  #pragma unroll
  for (int i = 0; i < 32; i += 8)
    tile[ty + i][tx] = L[(size_t)(s0 + ty + i) * T_DIM + (t0 + tx)];
  __syncthreads();
  unsigned short* P = probs + (size_t)bz * T_DIM * T_DIM;
  #pragma unroll
  for (int i = 0; i < 32; i += 8) {
    int t = t0 + ty + i, s = s0 + tx;
    float x = b2f(tile[tx][ty + i]);
    float p = (t >= s) ? __expf(x - smax[bz * T_DIM + s]) * sinv[bz * T_DIM + s] : 0.f;
    P[(size_t)t * T_DIM + s] = f2b(p);
  }
}

extern "C" void kernel_launch(void* const* d_in, const int* in_sizes, int n_in,
                              void* d_out, int out_size, void* d_ws, size_t ws_size,
                              hipStream_t stream) {
  const float* minibatch = (const float*)d_in[0];
  const float* emb_w   = (const float*)d_in[1];
  const float* emb_b   = (const float*)d_in[2];
  const float* key_w   = (const float*)d_in[3];
  const float* key_b   = (const float*)d_in[4];
  const float* query_w = (const float*)d_in[5];
  const float* query_b = (const float*)d_in[6];
  const float* value_w = (const float*)d_in[7];
  const float* value_b = (const float*)d_in[8];
  float* out = (float*)d_out;

  char* ws = (char*)d_ws;
  const size_t MB = 1ull << 20;
  unsigned short* wbf_emb = (unsigned short*)(ws + 0 * MB);    // 2 MB
  unsigned short* wbf_kqv = (unsigned short*)(ws + 2 * MB);    // 6 MB
  float*          kqv_b   = (float*)(ws + 8 * MB);
  unsigned short* m_bf    = (unsigned short*)(ws + 9 * MB);    // 16 MB
  unsigned short* KQV     = (unsigned short*)(ws + 25 * MB);   // 48 MB
  unsigned short* VT_bf   = (unsigned short*)(ws + 73 * MB);   // 16 MB
  unsigned short* logits_bf = (unsigned short*)(ws + 89 * MB); // 32 MB
  unsigned short* probs   = (unsigned short*)(ws + 153 * MB);  // 32 MB
  float*          smax    = (float*)(ws + 186 * MB);
  float*          sinv    = (float*)(ws + 186 * MB + 32768);

  const int BT = B_DIM * T_DIM;   // 8192
  const size_t TT = (size_t)T_DIM * T_DIM;

  // 1) weights -> bf16 + bias concat
  prep_kernel<<<4097, 256, 0, stream>>>(emb_w, key_w, query_w, value_w,
                                        key_b, query_b, value_b,
                                        wbf_emb, wbf_kqv, kqv_b);

  // 2) m = x^T @ emb_w^T + emb_b  (transpose fused into A-staging) -- 256 blocks
  embt_kernel<<<dim3(D_DIM / 256, BT / 128, 1), 512, 0, stream>>>(
      minibatch, wbf_emb, emb_b, m_bf);

  // 3) KQV = m @ [Wk;Wq;Wv]^T + b  -- 768 blocks = 3 exact rounds
  gemm8_kernel<1, true><<<dim3(3072 / 256, BT / 128, 1), 512, 0, stream>>>(
      m_bf, wbf_kqv, kqv_b, nullptr, KQV, 3072, D_DIM, D_DIM, D_DIM, 0, 0, 0);

  // 4) VT[b][d][t] = V[b][t][d]
  transpose_kernel<<<dim3(D_DIM / 32, T_DIM / 32, B_DIM), 256, 0, stream>>>(
      KQV + 2048, VT_bf, 3072, (size_t)T_DIM * 3072, T_DIM, (size_t)D_DIM * T_DIM);

  // 5) logitsT[b][s][t] = K[b,s]·Q[b,t]  -- 256^2 tiles, 144 working blocks (1 round)
  gemmL_kernel<<<dim3(T_DIM / 256, T_DIM / 256, B_DIM), 512, 0, stream>>>(
      KQV, KQV + 1024, logits_bf, T_DIM, D_DIM, 3072, 3072,
      (size_t)T_DIM * 3072, (size_t)T_DIM * 3072, TT);

  // 6) column-softmax stats
  softmax_stats_kernel<<<BT, 256, 0, stream>>>(logits_bf, smax, sinv);

  // 7) probs[b][t][s] bf16, transposed
  probs_kernel<<<dim3(T_DIM / 32, T_DIM / 32, B_DIM), 256, 0, stream>>>(
      logits_bf, smax, sinv, probs);

  // 8) paired PV + residual + output transpose (256 uniform blocks)
  pv_kernel<<<dim3(8, 8, B_DIM), 512, 0, stream>>>(probs, VT_bf, m_bf, out);
}

// Round 11
// 194.797 us; speedup vs baseline: 1.0938x; 1.0938x over previous
//
#include <hip/hip_runtime.h>

#define T_DIM 2048
#define D_DIM 1024
#define H_DIM 1024
#define B_DIM 4

typedef __attribute__((ext_vector_type(8))) __bf16 bf16x8;
typedef __attribute__((ext_vector_type(4))) float f32x4;
typedef __attribute__((ext_vector_type(8))) unsigned short us8;

__device__ __forceinline__ unsigned short f2b(float f) {
  union { float f; unsigned int u; } x; x.f = f;
  unsigned int r = x.u + 0x7fffu + ((x.u >> 16) & 1u);
  return (unsigned short)(r >> 16);
}
__device__ __forceinline__ float b2f(unsigned short b) {
  union { unsigned int u; float f; } x; x.u = ((unsigned int)b) << 16;
  return x.f;
}

__device__ __forceinline__ void async16(unsigned short* l, const unsigned short* g) {
  __builtin_amdgcn_global_load_lds((const __attribute__((address_space(1))) void*)g,
                                   (__attribute__((address_space(3))) void*)l,
                                   16, 0, 0);
}

// ---------------- fused weights prep: 4x f32->bf16 cvt + bias concat ----------------
__global__ __launch_bounds__(256) void prep_kernel(const float* __restrict__ ew,
                                                   const float* __restrict__ kw,
                                                   const float* __restrict__ qw,
                                                   const float* __restrict__ vw,
                                                   const float* __restrict__ kb,
                                                   const float* __restrict__ qb,
                                                   const float* __restrict__ vb,
                                                   unsigned short* __restrict__ oe,
                                                   unsigned short* __restrict__ okqv,
                                                   float* __restrict__ ob) {
  int bid = blockIdx.x;
  if (bid == 4096) {               // bias concat: 3072 floats
    #pragma unroll
    for (int k = 0; k < 3; k++) {
      int f4 = threadIdx.x + k * 256;
      int fi = f4 * 4;
      const float* src = fi < 1024 ? kb + fi : (fi < 2048 ? qb + (fi - 1024) : vb + (fi - 2048));
      *(float4*)(&ob[fi]) = *(const float4*)src;
    }
    return;
  }
  int i = bid * 256 + threadIdx.x;
  int seg = i >> 18;
  int off = i & 262143;
  const float* in = seg == 0 ? ew : (seg == 1 ? kw : (seg == 2 ? qw : vw));
  unsigned short* out = seg == 0 ? oe : okqv + (size_t)(seg - 1) * 1048576;
  float4 v = ((const float4*)in)[off];
  ushort4 o;
  o.x = f2b(v.x); o.y = f2b(v.y); o.z = f2b(v.z); o.w = f2b(v.w);
  ((ushort4*)out)[off] = o;
}

// ---------------- tiled transpose f32 -> bf16 (xT) ----------------
__global__ __launch_bounds__(256) void transpose_f32_kernel(const float* __restrict__ in,
                                                            unsigned short* __restrict__ out,
                                                            int inLD, size_t sIn, int R, size_t sOut) {
  __shared__ float tile[32][33];
  int c0 = blockIdx.x * 32, r0 = blockIdx.y * 32;
  int tx = threadIdx.x & 31, ty = threadIdx.x >> 5;
  const float* I = in + (size_t)blockIdx.z * sIn;
  #pragma unroll
  for (int i = 0; i < 32; i += 8)
    tile[ty + i][tx] = I[(size_t)(r0 + ty + i) * inLD + (c0 + tx)];
  __syncthreads();
  unsigned short* O = out + (size_t)blockIdx.z * sOut;
  #pragma unroll
  for (int i = 0; i < 32; i += 8)
    O[(size_t)(c0 + ty + i) * R + (r0 + tx)] = f2b(tile[tx][ty + i]);
}

#define BAR_ asm volatile("s_barrier" ::: "memory")
#define VM8_ asm volatile("s_waitcnt vmcnt(8)" ::: "memory")
#define VM6_ asm volatile("s_waitcnt vmcnt(6)" ::: "memory")
#define VM4_ asm volatile("s_waitcnt vmcnt(4)" ::: "memory")
#define VM0_ asm volatile("s_waitcnt vmcnt(0)" ::: "memory")

#define FRG(base, row, ks) \
  (*(const bf16x8*)((base) + (row) * 64 + ((((ks) << 2) | hi) ^ (lo & 7)) * 8))

// ============ 128x256 B^T GEMM, triple-buffered, 1 barrier / K-tile ============
// OMODE 1: bf16 out + column bias. OMODE 3: bf16 out + ROW bias (VT-direct).
#define STGA3(t, bb, u) async16(smem + (bb) * 24576 + (u) * 4096 + tid * 8, \
                                A + (size_t)((u) * 64 + rl0) * lda + (t) * 64 + ce)
#define STGB3(t, bb, u) async16(smem + (bb) * 24576 + 8192 + (u) * 4096 + tid * 8, \
                                Bm + (size_t)((u) * 64 + rl0) * ldb + (t) * 64 + ce)
#define STGTILE(t, bb) do { STGA3(t, bb, 0); STGA3(t, bb, 1); \
    STGB3(t, bb, 0); STGB3(t, bb, 1); STGB3(t, bb, 2); STGB3(t, bb, 3); } while (0)

#define LOADFRAGS(bA, bB)                                            \
  _Pragma("unroll") for (int m_ = 0; m_ < 4; m_++) {                 \
    af[m_][0] = FRG(bA, wr * 64 + m_ * 16 + lo, 0);                  \
    af[m_][1] = FRG(bA, wr * 64 + m_ * 16 + lo, 1);                  \
  }                                                                  \
  _Pragma("unroll") for (int n_ = 0; n_ < 4; n_++) {                 \
    bg[n_][0] = FRG(bB, wc * 64 + n_ * 16 + lo, 0);                  \
    bg[n_][1] = FRG(bB, wc * 64 + n_ * 16 + lo, 1);                  \
  }

#define MFMA32_                                                          \
  __builtin_amdgcn_s_setprio(1);                                         \
  _Pragma("unroll") for (int ks_ = 0; ks_ < 2; ks_++)                    \
    _Pragma("unroll") for (int m_ = 0; m_ < 4; m_++)                     \
      _Pragma("unroll") for (int n_ = 0; n_ < 4; n_++)                   \
        acc[m_][n_] = __builtin_amdgcn_mfma_f32_16x16x32_bf16(           \
            af[m_][ks_], bg[n_][ks_], acc[m_][n_], 0, 0, 0);             \
  __builtin_amdgcn_s_setprio(0);

template <int OMODE>
__global__ __launch_bounds__(512, 2)
void gemm8_kernel(const unsigned short* __restrict__ A,
                  const unsigned short* __restrict__ Bm,
                  const float* __restrict__ bias,
                  unsigned short* __restrict__ Cb,
                  int N, int K, int lda, int ldb) {
  __shared__ __align__(16) unsigned short smem[73728];   // 144 KiB

  int gx = gridDim.x;
  int nwg = gx * gridDim.y;
  int flat = blockIdx.x + gx * blockIdx.y;
  int cpx = nwg >> 3;
  int f2 = (flat & 7) * cpx + (flat >> 3);
  int bn = f2 % gx, bm = f2 / gx;

  A  += (size_t)bm * 128 * lda;
  Bm += (size_t)bn * 256 * ldb;

  int tid = threadIdx.x;
  int lane = tid & 63, wid = tid >> 6;
  int wr = wid >> 2, wc = wid & 3;
  int lo = lane & 15, hi = lane >> 4;
  int rl0 = tid >> 3;
  int ce = 8 * ((tid & 7) ^ (rl0 & 7));

  int nt = K / 64;

  bf16x8 af[4][2], bg[4][2];
  f32x4 acc[4][4] = {};

  STGTILE(0, 0);
  STGTILE(1, 1);
  VM6_; BAR_;

  int cur = 0;
  for (int t = 0; t < nt - 2; t++) {
    const unsigned short* bA = smem + cur * 24576;
    const unsigned short* bB = bA + 8192;
    LOADFRAGS(bA, bB)
    int b2 = cur + 2; if (b2 >= 3) b2 -= 3;
    STGTILE(t + 2, b2);
    MFMA32_
    VM6_; BAR_;
    cur = (cur + 1 == 3) ? 0 : cur + 1;
  }
  {
    const unsigned short* bA = smem + cur * 24576;
    const unsigned short* bB = bA + 8192;
    LOADFRAGS(bA, bB)
    MFMA32_
    VM0_; BAR_;
    cur = (cur + 1 == 3) ? 0 : cur + 1;
  }
  {
    const unsigned short* bA = smem + cur * 24576;
    const unsigned short* bB = bA + 8192;
    LOADFRAGS(bA, bB)
    MFMA32_
  }

  __syncthreads();
  int row0 = bm * 128, col0 = bn * 256;
  unsigned short* ep = smem;   // [128][264]
  #pragma unroll
  for (int n = 0; n < 4; n++) {
    int cl = wc * 64 + n * 16 + lo;
    float bvc = (OMODE == 1) ? bias[col0 + cl] : 0.f;
    #pragma unroll
    for (int m = 0; m < 4; m++) {
      int rl = wr * 64 + m * 16 + hi * 4;
      #pragma unroll
      for (int j = 0; j < 4; j++) {
        float bv = (OMODE == 3) ? bias[row0 + rl + j] : bvc;
        ep[(rl + j) * 264 + cl] = f2b(acc[m][n][j] + bv);
      }
    }
  }
  __syncthreads();
  #pragma unroll
  for (int it = 0; it < 8; it++) {
    int idx = it * 512 + tid, r = idx >> 5, c = idx & 31;
    *(uint4*)(Cb + (size_t)(row0 + r) * N + col0 + c * 8) =
        *(const uint4*)(ep + r * 264 + c * 8);
  }
}

// ============ gemmL: 256x256 8-phase (R7-validated ledger) ============
// BIAS: column bias. SKIP: causal block skip (bn<bm -> exit).
#define STGAH(t, h) do { \
    unsigned short* d_ = ldsA + ((t) & 1) * 16384 + (h) * 8192 + tid * 8;            \
    const unsigned short* s_ = A + (size_t)((h) * 128 + rl0) * lda + (t) * 64 + ce;  \
    async16(d_, s_); async16(d_ + 4096, s_ + (size_t)64 * lda); } while (0)
#define STGBH(t, h) do { \
    unsigned short* d_ = ldsB + ((t) & 1) * 16384 + (h) * 8192 + tid * 8;            \
    const unsigned short* s_ = Bm + (size_t)((h) * 128 + rl0) * ldb + (t) * 64 + ce; \
    async16(d_, s_); async16(d_ + 4096, s_ + (size_t)64 * ldb); } while (0)

#define LDA_(bA, mb)                                                   \
  _Pragma("unroll") for (int m_ = 0; m_ < 4; m_++) {                   \
    int row_ = wr * 128 + ((mb) + m_) * 16 + lo;                       \
    af[m_][0] = FRG(bA, row_, 0);                                      \
    af[m_][1] = FRG(bA, row_, 1);                                      \
  }

#define LDB_(bB, nb, bgv)                                              \
  _Pragma("unroll") for (int n_ = 0; n_ < 2; n_++) {                   \
    int row_ = wc * 64 + ((nb) + n_) * 16 + lo;                        \
    bgv[n_][0] = FRG(bB, row_, 0);                                     \
    bgv[n_][1] = FRG(bB, row_, 1);                                     \
  }

#define MM_(mb, nb, bgv)                                                             \
  __builtin_amdgcn_s_setprio(1);                                                     \
  _Pragma("unroll") for (int m_ = 0; m_ < 4; m_++)                                   \
    _Pragma("unroll") for (int n_ = 0; n_ < 2; n_++) {                               \
      acc[(mb) + m_][(nb) + n_] = __builtin_amdgcn_mfma_f32_16x16x32_bf16(           \
          af[m_][0], bgv[n_][0], acc[(mb) + m_][(nb) + n_], 0, 0, 0);                \
      acc[(mb) + m_][(nb) + n_] = __builtin_amdgcn_mfma_f32_16x16x32_bf16(           \
          af[m_][1], bgv[n_][1], acc[(mb) + m_][(nb) + n_], 0, 0, 0);                \
    }                                                                                \
  __builtin_amdgcn_s_setprio(0);

template <bool BIAS, bool SKIP>
__global__ __launch_bounds__(512, 2)
void gemmL_kernel(const unsigned short* __restrict__ A,
                  const unsigned short* __restrict__ Bm,
                  const float* __restrict__ bias,
                  unsigned short* __restrict__ Cb,
                  int N, int K, int lda, int ldb,
                  size_t sAb, size_t sBb, size_t sCb) {
  __shared__ __align__(16) unsigned short smem[65536];   // 128 KiB
  unsigned short* ldsA = smem;
  unsigned short* ldsB = smem + 32768;

  int gx = gridDim.x;
  int nwg = gx * gridDim.y;
  int flat = blockIdx.x + gx * blockIdx.y;
  int cpx = nwg >> 3;
  int f2x = (flat & 7) * cpx + (flat >> 3);
  int bn = f2x % gx, bm = f2x / gx;
  int bz = blockIdx.z;
  if (SKIP && bn < bm) return;       // causal skip (t-tile < s-tile)

  A  += (size_t)bz * sAb + (size_t)bm * 256 * lda;
  Bm += (size_t)bz * sBb + (size_t)bn * 256 * ldb;

  int tid = threadIdx.x;
  int lane = tid & 63, wid = tid >> 6;
  int wr = wid >> 2, wc = wid & 3;
  int lo = lane & 15, hi = lane >> 4;
  int rl0 = tid >> 3;
  int ce = 8 * ((tid & 7) ^ (rl0 & 7));

  int nt = K / 64;

  bf16x8 af[4][2], bg0[2][2], bg1[2][2];
  f32x4 acc[8][4] = {};

  STGAH(0, 0); STGAH(0, 1); STGBH(0, 0); STGBH(0, 1);
  STGAH(1, 0); STGAH(1, 1); STGBH(1, 0); STGBH(1, 1);
  VM8_; BAR_;

  const unsigned short* bA0 = ldsA;
  const unsigned short* bB0 = ldsB;
  const unsigned short* bA1 = ldsA + 16384;
  const unsigned short* bB1 = ldsB + 16384;

  int nIter = nt >> 1;
  for (int i = 0; i < nIter; i++) {
    bool last = (i == nIter - 1);
    int ta = 2 * i, tb = ta + 1;
    LDA_(bA0, 0) LDB_(bB0, 0, bg0)
    BAR_; MM_(0, 0, bg0) BAR_;
    LDB_(bB0, 2, bg1)
    BAR_; MM_(0, 2, bg1) BAR_;
    LDA_(bA0, 4)
    if (!last) STGBH(ta + 2, 0);
    BAR_; MM_(4, 0, bg0) BAR_;
    if (!last) { STGAH(ta + 2, 0); STGBH(ta + 2, 1); }
    BAR_; MM_(4, 2, bg1)
    if (last) { VM0_; } else { VM6_; }
    BAR_;
    LDA_(bA1, 0) LDB_(bB1, 0, bg0)
    if (!last) STGAH(ta + 2, 1);
    BAR_; MM_(0, 0, bg0) BAR_;
    LDB_(bB1, 2, bg1)
    BAR_; MM_(0, 2, bg1) BAR_;
    LDA_(bA1, 4)
    if (!last) STGBH(tb + 2, 0);
    BAR_; MM_(4, 0, bg0) BAR_;
    if (!last) { STGAH(tb + 2, 0); STGBH(tb + 2, 1); STGAH(tb + 2, 1); }
    BAR_; MM_(4, 2, bg1)
    if (!last) VM8_;
    BAR_;
  }

  __syncthreads();
  int row0 = bm * 256, col0 = bn * 256;
  size_t coff = (size_t)bz * sCb;
  unsigned short* ep = smem;   // [128][264], 2 halves
  #pragma unroll
  for (int half = 0; half < 2; half++) {
    __syncthreads();
    if (wr == half) {
      #pragma unroll
      for (int n = 0; n < 4; n++) {
        int cl = wc * 64 + n * 16 + lo;
        float bv = BIAS ? bias[col0 + cl] : 0.f;
        #pragma unroll
        for (int m = 0; m < 8; m++) {
          int rl = m * 16 + hi * 4;
          #pragma unroll
          for (int j = 0; j < 4; j++)
            ep[(rl + j) * 264 + cl] = f2b(acc[m][n][j] + bv);
        }
      }
    }
    __syncthreads();
    #pragma unroll
    for (int it = 0; it < 8; it++) {
      int idx = it * 512 + tid, r = idx >> 5, c = idx & 31;
      *(uint4*)(Cb + coff + (size_t)(row0 + half * 128 + r) * N + col0 + c * 8) =
          *(const uint4*)(ep + r * 264 + c * 8);
    }
  }
}

// ============ Paired causal PV (VTd layout: [1024 d][8192 bt]) ============
#define PSTGA(t, bb, u) async16(smem + (bb) * 16384 + (u) * 4096 + tid * 8, \
                                Ap + (size_t)((u) * 64 + rl0) * T_DIM + (t) * 64 + ce)
#define PSTGB(t, bb, u) async16(smem + (bb) * 16384 + 8192 + (u) * 4096 + tid * 8, \
                                Bp + (size_t)((u) * 64 + rl0) * 8192 + (t) * 64 + ce)
#define PSTG(t, bb) do { PSTGA(t, bb, 0); PSTGA(t, bb, 1); \
                         PSTGB(t, bb, 0); PSTGB(t, bb, 1); } while (0)

#define PVFRAGS(bA, bB)                                              \
  _Pragma("unroll") for (int m_ = 0; m_ < 4; m_++) {                 \
    af[m_][0] = FRG(bA, wr * 64 + m_ * 16 + lo, 0);                  \
    af[m_][1] = FRG(bA, wr * 64 + m_ * 16 + lo, 1);                  \
  }                                                                  \
  _Pragma("unroll") for (int n_ = 0; n_ < 2; n_++) {                 \
    bg[n_][0] = FRG(bB, wc * 32 + n_ * 16 + lo, 0);                  \
    bg[n_][1] = FRG(bB, wc * 32 + n_ * 16 + lo, 1);                  \
  }

#define PVMFMA_                                                          \
  __builtin_amdgcn_s_setprio(1);                                         \
  _Pragma("unroll") for (int ks_ = 0; ks_ < 2; ks_++)                    \
    _Pragma("unroll") for (int m_ = 0; m_ < 4; m_++)                     \
      _Pragma("unroll") for (int n_ = 0; n_ < 2; n_++)                   \
        acc[m_][n_] = __builtin_amdgcn_mfma_f32_16x16x32_bf16(           \
            af[m_][ks_], bg[n_][ks_], acc[m_][n_], 0, 0, 0);             \
  __builtin_amdgcn_s_setprio(0);

__global__ __launch_bounds__(512, 2)
void pv_kernel(const unsigned short* __restrict__ probs,
               const unsigned short* __restrict__ VTd,
               const unsigned short* __restrict__ mres,
               float* __restrict__ out) {
  __shared__ __align__(16) unsigned short smem[49152];   // 96 KiB
  int bn = blockIdx.x;        // d-tile (128 wide), 0..7
  int jj = blockIdx.y;        // pair id 0..7
  int bz = blockIdx.z;
  int tid = threadIdx.x;
  int lane = tid & 63, wid = tid >> 6;
  int wr = wid >> 2, wc = wid & 3;
  int lo = lane & 15, hi = lane >> 4;
  int rl0 = tid >> 3;
  int ce = 8 * ((tid & 7) ^ (rl0 & 7));

  const unsigned short* Bp = VTd + (size_t)(bn * 128) * 8192 + bz * T_DIM;

  #pragma unroll 1
  for (int seg = 0; seg < 2; seg++) {
    int jt = (seg == 0) ? jj : (15 - jj);
    int nt = ((seg == 0) ? (jj + 1) : (16 - jj)) * 2;
    const unsigned short* Ap = probs + (size_t)bz * T_DIM * T_DIM + (size_t)(jt * 128) * T_DIM;

    bf16x8 af[4][2], bg[2][2];
    f32x4 acc[4][2] = {};

    PSTG(0, 0);
    PSTG(1, 1);
    VM4_; BAR_;

    int cur = 0;
    for (int t = 0; t < nt - 2; t++) {
      const unsigned short* bA = smem + cur * 16384;
      const unsigned short* bB = bA + 8192;
      PVFRAGS(bA, bB)
      int b2 = cur + 2; if (b2 >= 3) b2 -= 3;
      PSTG(t + 2, b2);
      PVMFMA_
      VM4_; BAR_;
      cur = (cur + 1 == 3) ? 0 : cur + 1;
    }
    {
      const unsigned short* bA = smem + cur * 16384;
      const unsigned short* bB = bA + 8192;
      PVFRAGS(bA, bB)
      PVMFMA_
      VM0_; BAR_;
      cur = (cur + 1 == 3) ? 0 : cur + 1;
    }
    {
      const unsigned short* bA = smem + cur * 16384;
      const unsigned short* bB = bA + 8192;
      PVFRAGS(bA, bB)
      PVMFMA_
    }

    __syncthreads();
    float* ep = (float*)smem;   // [128 d][132 t]
    #pragma unroll
    for (int n = 0; n < 2; n++) {
      int dl = wc * 32 + n * 16 + lo;
      #pragma unroll
      for (int m = 0; m < 4; m++) {
        int tl = wr * 64 + m * 16 + hi * 4;
        #pragma unroll
        for (int j = 0; j < 4; j++) {
          float v = acc[m][n][j] +
              b2f(mres[((size_t)bz * T_DIM + jt * 128 + tl + j) * D_DIM + bn * 128 + dl]);
          ep[dl * 132 + tl + j] = v;
        }
      }
    }
    __syncthreads();
    #pragma unroll
    for (int it = 0; it < 8; it++) {
      int idx = it * 512 + tid, r = idx >> 5, c = idx & 31;
      *(float4*)(out + ((size_t)bz * D_DIM + bn * 128 + r) * T_DIM + jt * 128 + c * 4) =
          *(const float4*)(ep + r * 132 + c * 4);
    }
    __syncthreads();
  }
}

// ---------------- softmax stats (bf16 logitsT rows) ----------------
__device__ __forceinline__ float wred_max(float v) {
  #pragma unroll
  for (int o = 32; o > 0; o >>= 1) v = fmaxf(v, __shfl_down(v, o, 64));
  return v;
}
__device__ __forceinline__ float wred_sum(float v) {
  #pragma unroll
  for (int o = 32; o > 0; o >>= 1) v += __shfl_down(v, o, 64);
  return v;
}

__global__ __launch_bounds__(256) void softmax_stats_kernel(const unsigned short* __restrict__ lg,
                                                            float* __restrict__ smax,
                                                            float* __restrict__ sinv) {
  __shared__ float sb[4];
  int row = blockIdx.x;            // b*T + s
  int s = row & (T_DIM - 1);
  us8 v = ((const us8*)(lg + (size_t)row * T_DIM))[threadIdx.x];
  int tb = threadIdx.x * 8;
  float x[8];
  float mx = -3.4e38f;
  #pragma unroll
  for (int j = 0; j < 8; j++) {
    x[j] = (tb + j >= s) ? b2f(v[j]) : -3.4e38f;
    mx = fmaxf(mx, x[j]);
  }
  mx = wred_max(mx);
  if ((threadIdx.x & 63) == 0) sb[threadIdx.x >> 6] = mx;
  __syncthreads();
  mx = fmaxf(fmaxf(sb[0], sb[1]), fmaxf(sb[2], sb[3]));
  __syncthreads();
  float sum = 0.f;
  #pragma unroll
  for (int j = 0; j < 8; j++) sum += __expf(x[j] - mx);
  sum = wred_sum(sum);
  if ((threadIdx.x & 63) == 0) sb[threadIdx.x >> 6] = sum;
  __syncthreads();
  if (threadIdx.x == 0) {
    float tot = sb[0] + sb[1] + sb[2] + sb[3];
    smax[row] = mx;
    sinv[row] = 1.0f / (tot * 32.0f);
  }
}

// ---------------- normalize + transpose: probs[t][s] bf16 ----------------
__global__ __launch_bounds__(256) void probs_kernel(const unsigned short* __restrict__ lg,
                                                    const float* __restrict__ smax,
                                                    const float* __restrict__ sinv,
                                                    unsigned short* __restrict__ probs) {
  int bz = blockIdx.z;
  int t0 = blockIdx.x * 32, s0 = blockIdx.y * 32;
  if (s0 >= (((t0 >> 7) + 1) << 7)) return;
  __shared__ unsigned short tile[32][33];
  int tx = threadIdx.x & 31, ty = threadIdx.x >> 5;
  const unsigned short* L = lg + (size_t)bz * T_DIM * T_DIM;
  #pragma unroll
  for (int i = 0; i < 32; i += 8)
    tile[ty + i][tx] = L[(size_t)(s0 + ty + i) * T_DIM + (t0 + tx)];
  __syncthreads();
  unsigned short* P = probs + (size_t)bz * T_DIM * T_DIM;
  #pragma unroll
  for (int i = 0; i < 32; i += 8) {
    int t = t0 + ty + i, s = s0 + tx;
    float x = b2f(tile[tx][ty + i]);
    float p = (t >= s) ? __expf(x - smax[bz * T_DIM + s]) * sinv[bz * T_DIM + s] : 0.f;
    P[(size_t)t * T_DIM + s] = f2b(p);
  }
}

extern "C" void kernel_launch(void* const* d_in, const int* in_sizes, int n_in,
                              void* d_out, int out_size, void* d_ws, size_t ws_size,
                              hipStream_t stream) {
  const float* minibatch = (const float*)d_in[0];
  const float* emb_w   = (const float*)d_in[1];
  const float* emb_b   = (const float*)d_in[2];
  const float* key_w   = (const float*)d_in[3];
  const float* key_b   = (const float*)d_in[4];
  const float* query_w = (const float*)d_in[5];
  const float* query_b = (const float*)d_in[6];
  const float* value_w = (const float*)d_in[7];
  const float* value_b = (const float*)d_in[8];
  float* out = (float*)d_out;

  char* ws = (char*)d_ws;
  const size_t MB = 1ull << 20;
  unsigned short* wbf_emb = (unsigned short*)(ws + 0 * MB);    // 2 MB
  unsigned short* wbf_kqv = (unsigned short*)(ws + 2 * MB);    // 6 MB [key|query|value]
  float*          kqv_b   = (float*)(ws + 8 * MB);
  unsigned short* m_bf    = (unsigned short*)(ws + 9 * MB);    // 16 MB, live to end
  unsigned short* KQ      = (unsigned short*)(ws + 25 * MB);   // 32 MB [8192][2048]
  unsigned short* VTd     = (unsigned short*)(ws + 57 * MB);   // 16 MB [1024][8192]
  unsigned short* logits_bf = (unsigned short*)(ws + 89 * MB); // 32 MB
  unsigned short* xT      = (unsigned short*)(ws + 153 * MB);  // 16 MB (dead after emb)
  unsigned short* probs   = (unsigned short*)(ws + 153 * MB);  // 32 MB, aliases xT
  float*          smax    = (float*)(ws + 186 * MB);
  float*          sinv    = (float*)(ws + 186 * MB + 32768);

  const int BT = B_DIM * T_DIM;   // 8192
  const size_t TT = (size_t)T_DIM * T_DIM;

  // 1) weights -> bf16 + bias concat
  prep_kernel<<<4097, 256, 0, stream>>>(emb_w, key_w, query_w, value_w,
                                        key_b, query_b, value_b,
                                        wbf_emb, wbf_kqv, kqv_b);

  // 2) xT[b][t][h] = minibatch[b][h][t], bf16
  transpose_f32_kernel<<<dim3(T_DIM / 32, H_DIM / 32, B_DIM), 256, 0, stream>>>(
      minibatch, xT, T_DIM, (size_t)H_DIM * T_DIM, H_DIM, (size_t)T_DIM * H_DIM);

  // 3) m = xT @ emb_w^T + emb_b  -- 128x256 tile, 256 blocks, 1 round
  gemm8_kernel<1><<<dim3(D_DIM / 256, BT / 128, 1), 512, 0, stream>>>(
      xT, wbf_emb, emb_b, m_bf, D_DIM, H_DIM, H_DIM, H_DIM);

  // 4) KQ = m @ [Wk;Wq]^T + b  -- 256^2 8-phase, 256 blocks exact, 1 round
  gemmL_kernel<true, false><<<dim3(2048 / 256, BT / 256, 1), 512, 0, stream>>>(
      m_bf, wbf_kqv, kqv_b, KQ, 2048, D_DIM, D_DIM, D_DIM, 0, 0, 0);

  // 5) VTd[d][bt] = Wv[d]·m[bt] + vb[d]  -- 128x256 tile, 256 blocks, 1 round
  gemm8_kernel<3><<<dim3(BT / 256, D_DIM / 128, 1), 512, 0, stream>>>(
      wbf_kqv + 2 * 1024 * 1024, m_bf, value_b, VTd, BT, D_DIM, D_DIM, D_DIM);

  // 6) logitsT[b][s][t] = K[b,s]·Q[b,t]  -- 256^2 8-phase, causal skip
  gemmL_kernel<false, true><<<dim3(T_DIM / 256, T_DIM / 256, B_DIM), 512, 0, stream>>>(
      KQ, KQ + 1024, nullptr, logits_bf, T_DIM, D_DIM, 2048, 2048,
      (size_t)T_DIM * 2048, (size_t)T_DIM * 2048, TT);

  // 7) column-softmax stats
  softmax_stats_kernel<<<BT, 256, 0, stream>>>(logits_bf, smax, sinv);

  // 8) probs[b][t][s] bf16, transposed
  probs_kernel<<<dim3(T_DIM / 32, T_DIM / 32, B_DIM), 256, 0, stream>>>(
      logits_bf, smax, sinv, probs);

  // 9) paired PV + residual + output transpose (256 uniform blocks)
  pv_kernel<<<dim3(8, 8, B_DIM), 512, 0, stream>>>(probs, VTd, m_bf, out);
}